// Round 11
// baseline (4652.754 us; speedup 1.0000x reference)
//
#include <hip/hip_runtime.h>
#include <hip/hip_bf16.h>

// Problem constants (fixed by the harness).
#define N_B   128     // batch
#define L_SEQ 2048    // sequence length
#define H_DIM 256     // hidden
#define EMB   256     // embedding dim
#define G3    768     // 3 used gates (F, O, Htmp) * 256
#define G4    1024    // total gate rows
#define WROW  512     // W_w row length (H + Emb), C-order rows
#define V_SZ  32000   // vocab

// ROUND-11: output is FLOAT32 (reference output dtype; only inputs are
// bf16-ified by the harness). All prior rounds wrote bf16 ushorts — half the
// buffer, decorrelated comparison, and invisible diagnostics (r8's marker
// landed in mantissa bits). Layouts: canonical all-C, concat [h,x]
// (the r2/r9-verified function).

typedef unsigned short ushort_t;
typedef unsigned int   uint_t;

using f32x4  = __attribute__((ext_vector_type(4))) float;
using bf16x8 = __attribute__((ext_vector_type(8))) short;
using h2_t   = __attribute__((ext_vector_type(2))) _Float16;
using ushort4_t = __attribute__((ext_vector_type(4))) ushort_t;

__device__ __forceinline__ float bf2f(ushort_t u) {
  union { uint_t u; float f; } x; x.u = ((uint_t)u) << 16; return x.f;
}
__device__ __forceinline__ ushort_t f2bf(float f) {  // RNE f32 -> bf16
  union { float f; uint_t u; } x; x.f = f;
  return (ushort_t)((x.u + 0x7fffu + ((x.u >> 16) & 1u)) >> 16);
}
__device__ __forceinline__ float rcp_f(float x) {
#if __has_builtin(__builtin_amdgcn_rcpf)
  return __builtin_amdgcn_rcpf(x);
#else
  return 1.0f / x;
#endif
}
__device__ __forceinline__ float clampf(float x, float lo, float hi) {
  return fminf(fmaxf(x, lo), hi);
}
__device__ __forceinline__ float sigmoid_f(float x) {
  x = clampf(x, -30.f, 30.f);
  return rcp_f(1.0f + __expf(-x));
}
__device__ __forceinline__ float tanh_f(float x) {
  x = clampf(x, -15.f, 15.f);   // exact: tanh saturates well before 15
  float e = __expf(-2.0f * x);
  return (1.0f - e) * rcp_f(1.0f + e);
}
__device__ __forceinline__ float fdot2_f(h2_t a, h2_t b, float c) {
#if __has_builtin(__builtin_amdgcn_fdot2)
  return __builtin_amdgcn_fdot2(a, b, c, false);
#else
  return c + (float)a.x * (float)b.x + (float)a.y * (float)b.y;
#endif
}
__device__ __forceinline__ uint_t lane_bcast(uint_t v, int l) {
#if __has_builtin(__builtin_amdgcn_readlane)
  return (uint_t)__builtin_amdgcn_readlane((int)v, l);
#else
  return (uint_t)__shfl((int)v, l, 64);
#endif
}
// bf16 pair (packed dword, little-endian) -> f16 pair (exact: bf16->f16 lossless
// for normal range; denormal tail is negligible at these magnitudes)
__device__ __forceinline__ h2_t bfpair_to_h2(uint_t u) {
  union { uint_t u; float f; } lo, hi;
  lo.u = u << 16;
  hi.u = u & 0xffff0000u;
  h2_t r; r.x = (_Float16)lo.f; r.y = (_Float16)hi.f; return r;
}

// gate col g in [0,768) -> W_w row: F=g, O=512+(g-256), T=768+(g-512)
__device__ __forceinline__ int gmap(int g) { return (g < 256) ? g : g + 256; }

// ---------------------------------------------------------------------------
// Phase 0: dtype probe. flags[0]=E-is-f32, flags[1]=X-is-int64,
// flags[2]=W-is-f32. Exponent-sanity margins are astronomical; validated
// behaviorally (wrong branch would clamp-saturate; observed sigma is right).
// ---------------------------------------------------------------------------
__global__ void dtype_probe(const uint_t* __restrict__ Ed,
                            const uint_t* __restrict__ Xd,
                            const uint_t* __restrict__ Wd,
                            uint_t* __restrict__ flags) {
  if (threadIdx.x != 0 || blockIdx.x != 0) return;
  int saneE = 0, saneW = 0;
  for (int i = 0; i < 256; ++i) {
    uint_t le = Ed[i] & 0xffffu, ee = (le >> 7) & 0xffu;
    if (ee == 0u || (ee >= 90u && ee <= 126u)) saneE++;
    uint_t lw = Wd[i] & 0xffffu, ew = (lw >> 7) & 0xffu;
    if (ew == 0u || (ew >= 90u && ew <= 126u)) saneW++;
  }
  uint_t nz = 0u;
  for (int i = 0; i < 128; ++i) nz |= Xd[2 * i + 1];
  flags[0] = (saneE < 192) ? 1u : 0u;   // 1 = f32
  flags[1] = (nz == 0u) ? 1u : 0u;      // 1 = int64
  flags[2] = (saneW < 192) ? 1u : 0u;   // 1 = f32
}

// ---------------------------------------------------------------------------
// Phase 1: Eg[v, g] = sum_k E[v,k] * W_w[gmap(g), 256+k] + W_b[gmap(g)]
// (32000 x 768) = (32000 x 256) @ (256 x 768), bf16 MFMA, f16 output in ws.
// Function verified: r2 (this kernel) == r3 (VALU) == r9 (naive f32),
// bit-identical packed outputs. MFMA 16x16x32 bf16 layouts (m89):
//   A: lane holds A[m=lane&15][k=(lane>>4)*8+j]; B: B[k=(lane>>4)*8+j][n=lane&15]
//   C: C[row=(lane>>4)*4+j][col=lane&15]
// ---------------------------------------------------------------------------
__global__ __launch_bounds__(256) void eg_gemm(const void* __restrict__ Ein,
                                               const void* __restrict__ Wwin,
                                               const void* __restrict__ Wbin,
                                               _Float16* __restrict__ Eg,
                                               const uint_t* __restrict__ flags) {
  __shared__ __align__(16) ushort_t At[16][264];  // 16 x (256+8 pad) bf16
  const int tid = threadIdx.x;
  const int v0  = blockIdx.x * 16;
  const uint_t ef32 = flags[0];
  const uint_t wf32 = flags[2];

  if (!ef32) {
    const ushort_t* E = (const ushort_t*)Ein;
#pragma unroll
    for (int i = 0; i < 2; ++i) {
      int idx = tid + i * 256;           // 0..511
      int row = idx >> 5, seg = idx & 31;
      const uint4* src = (const uint4*)(E + (size_t)(v0 + row) * EMB + seg * 8);
      *(uint4*)&At[row][seg * 8] = *src;
    }
  } else {
    const float* Ef = (const float*)Ein;
#pragma unroll
    for (int i = 0; i < 4; ++i) {
      int idx = tid + i * 256;           // 0..1023
      int row = idx >> 6, seg = idx & 63;
      float4 v = *(const float4*)(Ef + (size_t)(v0 + row) * EMB + seg * 4);
      ushort4_t s;
      s.x = f2bf(v.x); s.y = f2bf(v.y); s.z = f2bf(v.z); s.w = f2bf(v.w);
      *(ushort4_t*)&At[row][seg * 4] = s;
    }
  }
  __syncthreads();

  const int lane = tid & 63, wv = tid >> 6;
  const int m = lane & 15, q = lane >> 4;

  f32x4 acc[12];
#pragma unroll
  for (int nt = 0; nt < 12; ++nt) acc[nt] = f32x4{0.f, 0.f, 0.f, 0.f};

  if (!wf32) {
    const ushort_t* Ww = (const ushort_t*)Wwin;
#pragma unroll
    for (int kt = 0; kt < 8; ++kt) {
      bf16x8 a = *(const bf16x8*)&At[m][kt * 32 + q * 8];
#pragma unroll
      for (int nt = 0; nt < 12; ++nt) {
        int g  = wv * 192 + nt * 16 + m;
        int gr = gmap(g);
        const bf16x8* bp =
            (const bf16x8*)(Ww + (size_t)gr * WROW + EMB + kt * 32 + q * 8);
        acc[nt] = __builtin_amdgcn_mfma_f32_16x16x32_bf16(a, *bp, acc[nt], 0, 0, 0);
      }
    }
  } else {
    const float* Wf = (const float*)Wwin;
#pragma unroll
    for (int kt = 0; kt < 8; ++kt) {
      bf16x8 a = *(const bf16x8*)&At[m][kt * 32 + q * 8];
#pragma unroll
      for (int nt = 0; nt < 12; ++nt) {
        int g  = wv * 192 + nt * 16 + m;
        int gr = gmap(g);
        const float* wp = Wf + (size_t)gr * WROW + EMB + kt * 32 + q * 8;
        float4 w0 = *(const float4*)(wp);
        float4 w1 = *(const float4*)(wp + 4);
        bf16x8 b;
        b[0] = (short)f2bf(w0.x); b[1] = (short)f2bf(w0.y);
        b[2] = (short)f2bf(w0.z); b[3] = (short)f2bf(w0.w);
        b[4] = (short)f2bf(w1.x); b[5] = (short)f2bf(w1.y);
        b[6] = (short)f2bf(w1.z); b[7] = (short)f2bf(w1.w);
        acc[nt] = __builtin_amdgcn_mfma_f32_16x16x32_bf16(a, b, acc[nt], 0, 0, 0);
      }
    }
  }

#pragma unroll
  for (int nt = 0; nt < 12; ++nt) {
    int g  = wv * 192 + nt * 16 + m;
    int gr = gmap(g);
    float bias = wf32 ? ((const float*)Wbin)[gr] : bf2f(((const ushort_t*)Wbin)[gr]);
#pragma unroll
    for (int j = 0; j < 4; ++j) {
      int v = v0 + q * 4 + j;
      Eg[(size_t)v * G3 + g] = (_Float16)(acc[nt][j] + bias);
    }
  }
}

// ---------------------------------------------------------------------------
// Phase 2: recurrence. One block per chain (128 blocks, 256 threads). Thread
// j owns hidden col j: gate rows {j, 512+j, 768+j} h-part (cols 0:256) in
// 384 VGPRs as f16x2. h ping-pongs through LDS; pairs broadcast via readlane
// into fdot2 (f32 accum). OUTPUT: f32, C-order (n, j).
// ---------------------------------------------------------------------------
__global__ __launch_bounds__(256, 1) void lstm_rec(const int* __restrict__ Xi,
                                                   const void* __restrict__ Wwin,
                                                   const _Float16* __restrict__ Eg,
                                                   float* __restrict__ out,
                                                   const uint_t* __restrict__ flags) {
  __shared__ uint_t hbuf[2][128];
  const int tid  = threadIdx.x;
  const int lane = tid & 63;
  const int n    = blockIdx.x;
  const uint_t wf32 = flags[2];
  const uint_t x64  = flags[1];

  h2_t wF[128], wO[128], wT[128];
  if (!wf32) {
    const uint_t* rF = (const uint_t*)((const ushort_t*)Wwin + (size_t)(tid)       * WROW);
    const uint_t* rO = (const uint_t*)((const ushort_t*)Wwin + (size_t)(512 + tid) * WROW);
    const uint_t* rT = (const uint_t*)((const ushort_t*)Wwin + (size_t)(768 + tid) * WROW);
#pragma unroll
    for (int k = 0; k < 128; ++k) {
      wF[k] = bfpair_to_h2(rF[k]);
      wO[k] = bfpair_to_h2(rO[k]);
      wT[k] = bfpair_to_h2(rT[k]);
    }
  } else {
    const float* rF = (const float*)Wwin + (size_t)(tid)       * WROW;
    const float* rO = (const float*)Wwin + (size_t)(512 + tid) * WROW;
    const float* rT = (const float*)Wwin + (size_t)(768 + tid) * WROW;
#pragma unroll
    for (int k = 0; k < 128; ++k) {
      float2 vF = *(const float2*)(rF + 2 * k);
      float2 vO = *(const float2*)(rO + 2 * k);
      float2 vT = *(const float2*)(rT + 2 * k);
      wF[k].x = (_Float16)vF.x; wF[k].y = (_Float16)vF.y;
      wO[k].x = (_Float16)vO.x; wO[k].y = (_Float16)vO.y;
      wT[k].x = (_Float16)vT.x; wT[k].y = (_Float16)vT.y;
    }
  }

  if (tid < 128) hbuf[0][tid] = 0u;  // h_0 = 0

  float c = 0.f, hlast = 0.f;
  const size_t xbase = (size_t)n * L_SEQ;

  int tok0 = x64 ? Xi[xbase * 2] : Xi[xbase];
  if ((uint_t)tok0 >= (uint_t)V_SZ) tok0 = 0;
  const _Float16* eg0 = Eg + (size_t)tok0 * G3 + tid;
  float pxF = (float)eg0[0], pxO = (float)eg0[256], pxT = (float)eg0[512];

  for (int t = 0; t < L_SEQ; ++t) {
    __syncthreads();  // publishes h_t from end of previous step

    uint_t h0 = hbuf[t & 1][lane];
    uint_t h1 = hbuf[t & 1][64 + lane];

    float aF0 = pxF, aO0 = pxO, aT0 = pxT;
    float aF1 = 0.f, aO1 = 0.f, aT1 = 0.f;

    // Prefetch step t+1 x-projection (hidden behind the dot phase).
    {
      int tp = (t + 1 < L_SEQ) ? (t + 1) : (L_SEQ - 1);
      int tok = x64 ? Xi[(xbase + tp) * 2] : Xi[xbase + tp];
      if ((uint_t)tok >= (uint_t)V_SZ) tok = 0;
      const _Float16* e = Eg + (size_t)tok * G3 + tid;
      pxF = (float)e[0]; pxO = (float)e[256]; pxT = (float)e[512];
    }

#pragma unroll
    for (int k = 0; k < 64; ++k) {
      h2_t hh = __builtin_bit_cast(h2_t, lane_bcast(h0, k));
      if (k & 1) {
        aF1 = fdot2_f(wF[k], hh, aF1);
        aO1 = fdot2_f(wO[k], hh, aO1);
        aT1 = fdot2_f(wT[k], hh, aT1);
      } else {
        aF0 = fdot2_f(wF[k], hh, aF0);
        aO0 = fdot2_f(wO[k], hh, aO0);
        aT0 = fdot2_f(wT[k], hh, aT0);
      }
    }
#pragma unroll
    for (int k = 0; k < 64; ++k) {
      h2_t hh = __builtin_bit_cast(h2_t, lane_bcast(h1, k));
      int kk = k + 64;
      if (k & 1) {
        aF1 = fdot2_f(wF[kk], hh, aF1);
        aO1 = fdot2_f(wO[kk], hh, aO1);
        aT1 = fdot2_f(wT[kk], hh, aT1);
      } else {
        aF0 = fdot2_f(wF[kk], hh, aF0);
        aO0 = fdot2_f(wO[kk], hh, aO0);
        aT0 = fdot2_f(wT[kk], hh, aT0);
      }
    }

    float aF = aF0 + aF1, aO = aO0 + aO1, aT = aT0 + aT1;
    float Fg = sigmoid_f(aF);
    float Og = sigmoid_f(aO);
    float Tg = tanh_f(aT);
    c = Fg * c + Og * Tg;          // faithful to ref: uses O-gate, not I-gate
    float hv = Og * tanh_f(c);
    hlast = hv;

    ((_Float16*)hbuf[(t + 1) & 1])[tid] = (_Float16)hv;
  }

  // FLOAT32 output, C-order (n, j).
  out[(size_t)n * H_DIM + tid] = hlast;
}

extern "C" void kernel_launch(void* const* d_in, const int* in_sizes, int n_in,
                              void* d_out, int out_size, void* d_ws, size_t ws_size,
                              hipStream_t stream) {
  const void* X  = d_in[0];
  const void* E  = d_in[1];
  const void* Ww = d_in[2];
  const void* Wb = d_in[3];
  for (int i = 0; i < n_in && i < 4; ++i) {
    switch (in_sizes[i]) {
      case N_B * L_SEQ: X  = d_in[i]; break;   // 262144
      case V_SZ * EMB:  E  = d_in[i]; break;   // 8192000
      case G4 * WROW:   Ww = d_in[i]; break;   // 524288
      case G4:          Wb = d_in[i]; break;   // 1024
      default: break;
    }
  }
  float* out = (float*)d_out;

  // ws: [0,256) flags | [256, ...) Eg (32000*768 f16 = 46.9 MiB; capacity
  // confirmed by r2 == r9 bit-identity).
  uint_t*   flags = (uint_t*)d_ws;
  _Float16* Eg    = (_Float16*)((char*)d_ws + 256);

  dtype_probe<<<dim3(1), dim3(64), 0, stream>>>(
      (const uint_t*)E, (const uint_t*)X, (const uint_t*)Ww, flags);
  eg_gemm<<<dim3(V_SZ / 16), dim3(256), 0, stream>>>(E, Ww, Wb, Eg, flags);
  lstm_rec<<<dim3(N_B), dim3(256), 0, stream>>>((const int*)X, Ww, Eg, out, flags);
}

// Round 12
// 3007.347 us; speedup vs baseline: 1.5471x; 1.5471x over previous
//
#include <hip/hip_runtime.h>
#include <hip/hip_bf16.h>

// Problem constants (fixed by the harness).
#define N_B   128     // batch
#define L_SEQ 2048    // sequence length
#define H_DIM 256     // hidden
#define EMB   256     // embedding dim
#define G3    768     // 3 used gates (F, O, Htmp) * 256
#define G4    1024    // total gate rows
#define WROW  512     // W_w row length (H + Emb), C-order rows
#define V_SZ  32000   // vocab

// R12: r11 PASSED (absmax 6.1e-5). This round: fix the VGPR remat in
// lstm_rec (r11: VGPR_Count=204 vs 384 needed -> weights re-fetched every
// step; FETCH 184MB, VALUBusy 33%). K-split across 512 threads: 192 weight
// dwords/thread, under the 256-VGPR cap of __launch_bounds__(512,2).

typedef unsigned short ushort_t;
typedef unsigned int   uint_t;

using f32x4  = __attribute__((ext_vector_type(4))) float;
using bf16x8 = __attribute__((ext_vector_type(8))) short;
using h2_t   = __attribute__((ext_vector_type(2))) _Float16;
using ushort4_t = __attribute__((ext_vector_type(4))) ushort_t;

__device__ __forceinline__ float bf2f(ushort_t u) {
  union { uint_t u; float f; } x; x.u = ((uint_t)u) << 16; return x.f;
}
__device__ __forceinline__ ushort_t f2bf(float f) {  // RNE f32 -> bf16
  union { float f; uint_t u; } x; x.f = f;
  return (ushort_t)((x.u + 0x7fffu + ((x.u >> 16) & 1u)) >> 16);
}
__device__ __forceinline__ float rcp_f(float x) {
#if __has_builtin(__builtin_amdgcn_rcpf)
  return __builtin_amdgcn_rcpf(x);
#else
  return 1.0f / x;
#endif
}
__device__ __forceinline__ float clampf(float x, float lo, float hi) {
  return fminf(fmaxf(x, lo), hi);
}
__device__ __forceinline__ float sigmoid_f(float x) {
  x = clampf(x, -30.f, 30.f);
  return rcp_f(1.0f + __expf(-x));
}
__device__ __forceinline__ float tanh_f(float x) {
  x = clampf(x, -15.f, 15.f);   // exact: tanh saturates well before 15
  float e = __expf(-2.0f * x);
  return (1.0f - e) * rcp_f(1.0f + e);
}
__device__ __forceinline__ float fdot2_f(h2_t a, h2_t b, float c) {
#if __has_builtin(__builtin_amdgcn_fdot2)
  return __builtin_amdgcn_fdot2(a, b, c, false);
#else
  return c + (float)a.x * (float)b.x + (float)a.y * (float)b.y;
#endif
}
__device__ __forceinline__ uint_t lane_bcast(uint_t v, int l) {
#if __has_builtin(__builtin_amdgcn_readlane)
  return (uint_t)__builtin_amdgcn_readlane((int)v, l);
#else
  return (uint_t)__shfl((int)v, l, 64);
#endif
}
// bf16 pair (packed dword, little-endian) -> f16 pair (exact for normal range)
__device__ __forceinline__ h2_t bfpair_to_h2(uint_t u) {
  union { uint_t u; float f; } lo, hi;
  lo.u = u << 16;
  hi.u = u & 0xffff0000u;
  h2_t r; r.x = (_Float16)lo.f; r.y = (_Float16)hi.f; return r;
}

// gate col g in [0,768) -> W_w row: F=g, O=512+(g-256), T=768+(g-512)
__device__ __forceinline__ int gmap(int g) { return (g < 256) ? g : g + 256; }

// ---------------------------------------------------------------------------
// Phase 0: dtype probe (validated: r11 passed using these flags).
// ---------------------------------------------------------------------------
__global__ void dtype_probe(const uint_t* __restrict__ Ed,
                            const uint_t* __restrict__ Xd,
                            const uint_t* __restrict__ Wd,
                            uint_t* __restrict__ flags) {
  if (threadIdx.x != 0 || blockIdx.x != 0) return;
  int saneE = 0, saneW = 0;
  for (int i = 0; i < 256; ++i) {
    uint_t le = Ed[i] & 0xffffu, ee = (le >> 7) & 0xffu;
    if (ee == 0u || (ee >= 90u && ee <= 126u)) saneE++;
    uint_t lw = Wd[i] & 0xffffu, ew = (lw >> 7) & 0xffu;
    if (ew == 0u || (ew >= 90u && ew <= 126u)) saneW++;
  }
  uint_t nz = 0u;
  for (int i = 0; i < 128; ++i) nz |= Xd[2 * i + 1];
  flags[0] = (saneE < 192) ? 1u : 0u;   // 1 = f32
  flags[1] = (nz == 0u) ? 1u : 0u;      // 1 = int64
  flags[2] = (saneW < 192) ? 1u : 0u;   // 1 = f32
}

// ---------------------------------------------------------------------------
// Phase 1: Eg[v, g] = sum_k E[v,k] * W_w[gmap(g), 256+k] + W_b[gmap(g)]
// (unchanged from r11 — verified end-to-end, ~tens of µs)
// ---------------------------------------------------------------------------
__global__ __launch_bounds__(256) void eg_gemm(const void* __restrict__ Ein,
                                               const void* __restrict__ Wwin,
                                               const void* __restrict__ Wbin,
                                               _Float16* __restrict__ Eg,
                                               const uint_t* __restrict__ flags) {
  __shared__ __align__(16) ushort_t At[16][264];  // 16 x (256+8 pad) bf16
  const int tid = threadIdx.x;
  const int v0  = blockIdx.x * 16;
  const uint_t ef32 = flags[0];
  const uint_t wf32 = flags[2];

  if (!ef32) {
    const ushort_t* E = (const ushort_t*)Ein;
#pragma unroll
    for (int i = 0; i < 2; ++i) {
      int idx = tid + i * 256;           // 0..511
      int row = idx >> 5, seg = idx & 31;
      const uint4* src = (const uint4*)(E + (size_t)(v0 + row) * EMB + seg * 8);
      *(uint4*)&At[row][seg * 8] = *src;
    }
  } else {
    const float* Ef = (const float*)Ein;
#pragma unroll
    for (int i = 0; i < 4; ++i) {
      int idx = tid + i * 256;           // 0..1023
      int row = idx >> 6, seg = idx & 63;
      float4 v = *(const float4*)(Ef + (size_t)(v0 + row) * EMB + seg * 4);
      ushort4_t s;
      s.x = f2bf(v.x); s.y = f2bf(v.y); s.z = f2bf(v.z); s.w = f2bf(v.w);
      *(ushort4_t*)&At[row][seg * 4] = s;
    }
  }
  __syncthreads();

  const int lane = tid & 63, wv = tid >> 6;
  const int m = lane & 15, q = lane >> 4;

  f32x4 acc[12];
#pragma unroll
  for (int nt = 0; nt < 12; ++nt) acc[nt] = f32x4{0.f, 0.f, 0.f, 0.f};

  if (!wf32) {
    const ushort_t* Ww = (const ushort_t*)Wwin;
#pragma unroll
    for (int kt = 0; kt < 8; ++kt) {
      bf16x8 a = *(const bf16x8*)&At[m][kt * 32 + q * 8];
#pragma unroll
      for (int nt = 0; nt < 12; ++nt) {
        int g  = wv * 192 + nt * 16 + m;
        int gr = gmap(g);
        const bf16x8* bp =
            (const bf16x8*)(Ww + (size_t)gr * WROW + EMB + kt * 32 + q * 8);
        acc[nt] = __builtin_amdgcn_mfma_f32_16x16x32_bf16(a, *bp, acc[nt], 0, 0, 0);
      }
    }
  } else {
    const float* Wf = (const float*)Wwin;
#pragma unroll
    for (int kt = 0; kt < 8; ++kt) {
      bf16x8 a = *(const bf16x8*)&At[m][kt * 32 + q * 8];
#pragma unroll
      for (int nt = 0; nt < 12; ++nt) {
        int g  = wv * 192 + nt * 16 + m;
        int gr = gmap(g);
        const float* wp = Wf + (size_t)gr * WROW + EMB + kt * 32 + q * 8;
        float4 w0 = *(const float4*)(wp);
        float4 w1 = *(const float4*)(wp + 4);
        bf16x8 b;
        b[0] = (short)f2bf(w0.x); b[1] = (short)f2bf(w0.y);
        b[2] = (short)f2bf(w0.z); b[3] = (short)f2bf(w0.w);
        b[4] = (short)f2bf(w1.x); b[5] = (short)f2bf(w1.y);
        b[6] = (short)f2bf(w1.z); b[7] = (short)f2bf(w1.w);
        acc[nt] = __builtin_amdgcn_mfma_f32_16x16x32_bf16(a, b, acc[nt], 0, 0, 0);
      }
    }
  }

#pragma unroll
  for (int nt = 0; nt < 12; ++nt) {
    int g  = wv * 192 + nt * 16 + m;
    int gr = gmap(g);
    float bias = wf32 ? ((const float*)Wbin)[gr] : bf2f(((const ushort_t*)Wbin)[gr]);
#pragma unroll
    for (int j = 0; j < 4; ++j) {
      int v = v0 + q * 4 + j;
      Eg[(size_t)v * G3 + g] = (_Float16)(acc[nt][j] + bias);
    }
  }
}

// ---------------------------------------------------------------------------
// Phase 2 (R12): recurrence, 512 threads/block, K-SPLIT to kill VGPR remat.
// Thread (half, j): half = tid>>8 (wave-uniform), j = tid&255 = hidden col.
//   half 0: W rows {j,512+j,768+j} cols   0:128 -> 192 weight dwords (f16x2)
//   half 1: same rows,              cols 128:256 -> 192 weight dwords
// h (256 f16 = 128 dwords) in LDS; each wave loads its half (64 dwords) into
// 1 VGPR; readlane-broadcast pairs feed fdot2 (f32 accum). half-1 partials
// combined via LDS pbuf; half-0 does gates/c/h epilogue. 2 barriers/step.
// ---------------------------------------------------------------------------
__global__ __launch_bounds__(512, 2) void lstm_rec(const int* __restrict__ Xi,
                                                   const void* __restrict__ Wwin,
                                                   const _Float16* __restrict__ Eg,
                                                   float* __restrict__ out,
                                                   const uint_t* __restrict__ flags) {
  __shared__ uint_t hbuf[2][128];
  __shared__ float  pbuf[G3];
  const int tid  = threadIdx.x;          // 0..511
  const int lane = tid & 63;
  const int half = tid >> 8;             // 0 or 1 (wave-uniform)
  const int j    = tid & 255;            // hidden column
  const int n    = blockIdx.x;
  const uint_t wf32 = flags[2];
  const uint_t x64  = flags[1];

  // 192 weight dwords per thread (64 per gate), cols half*128 : half*128+128.
  h2_t wF[64], wO[64], wT[64];
  if (!wf32) {
    const uint_t* rF = (const uint_t*)((const ushort_t*)Wwin + (size_t)(j)       * WROW + half * 128);
    const uint_t* rO = (const uint_t*)((const ushort_t*)Wwin + (size_t)(512 + j) * WROW + half * 128);
    const uint_t* rT = (const uint_t*)((const ushort_t*)Wwin + (size_t)(768 + j) * WROW + half * 128);
#pragma unroll
    for (int d = 0; d < 64; ++d) {
      wF[d] = bfpair_to_h2(rF[d]);
      wO[d] = bfpair_to_h2(rO[d]);
      wT[d] = bfpair_to_h2(rT[d]);
    }
  } else {
    const float* rF = (const float*)Wwin + (size_t)(j)       * WROW + half * 128;
    const float* rO = (const float*)Wwin + (size_t)(512 + j) * WROW + half * 128;
    const float* rT = (const float*)Wwin + (size_t)(768 + j) * WROW + half * 128;
#pragma unroll
    for (int d = 0; d < 64; ++d) {
      float2 vF = *(const float2*)(rF + 2 * d);
      float2 vO = *(const float2*)(rO + 2 * d);
      float2 vT = *(const float2*)(rT + 2 * d);
      wF[d].x = (_Float16)vF.x; wF[d].y = (_Float16)vF.y;
      wO[d].x = (_Float16)vO.x; wO[d].y = (_Float16)vO.y;
      wT[d].x = (_Float16)vT.x; wT[d].y = (_Float16)vT.y;
    }
  }

  if (tid < 128) hbuf[0][tid] = 0u;  // h_0 = 0

  float c = 0.f, hlast = 0.f;
  const size_t xbase = (size_t)n * L_SEQ;

  // px(t=0), half-0 only (wave-uniform branch).
  float pxF = 0.f, pxO = 0.f, pxT = 0.f;
  if (half == 0) {
    int tok0 = x64 ? Xi[xbase * 2] : Xi[xbase];
    if ((uint_t)tok0 >= (uint_t)V_SZ) tok0 = 0;
    const _Float16* e = Eg + (size_t)tok0 * G3 + j;
    pxF = (float)e[0]; pxO = (float)e[256]; pxT = (float)e[512];
  }

  int cur = 0;
  for (int t = 0; t < L_SEQ; ++t) {
    __syncthreads();  // h(t) in hbuf[cur] published; pbuf free for this step

    const uint_t hv = hbuf[cur][half * 64 + lane];  // my half's h dwords

    // Prefetch px(t+1) (half-0), hidden behind the dot phase.
    float nF = 0.f, nO = 0.f, nT = 0.f;
    if (half == 0) {
      int tp = (t + 1 < L_SEQ) ? (t + 1) : (L_SEQ - 1);
      int tok = x64 ? Xi[(xbase + tp) * 2] : Xi[xbase + tp];
      if ((uint_t)tok >= (uint_t)V_SZ) tok = 0;
      const _Float16* e = Eg + (size_t)tok * G3 + j;
      nF = (float)e[0]; nO = (float)e[256]; nT = (float)e[512];
    }

    float aF0 = 0.f, aO0 = 0.f, aT0 = 0.f;
    float aF1 = 0.f, aO1 = 0.f, aT1 = 0.f;
#pragma unroll
    for (int d = 0; d < 64; ++d) {
      h2_t hh = __builtin_bit_cast(h2_t, lane_bcast(hv, d));
      if (d & 1) {
        aF1 = fdot2_f(wF[d], hh, aF1);
        aO1 = fdot2_f(wO[d], hh, aO1);
        aT1 = fdot2_f(wT[d], hh, aT1);
      } else {
        aF0 = fdot2_f(wF[d], hh, aF0);
        aO0 = fdot2_f(wO[d], hh, aO0);
        aT0 = fdot2_f(wT[d], hh, aT0);
      }
    }
    float aF = aF0 + aF1, aO = aO0 + aO1, aT = aT0 + aT1;

    if (half == 1) {
      pbuf[j]       = aF;
      pbuf[256 + j] = aO;
      pbuf[512 + j] = aT;
    }
    __syncthreads();  // partials ready

    if (half == 0) {
      aF += pbuf[j]       + pxF;
      aO += pbuf[256 + j] + pxO;
      aT += pbuf[512 + j] + pxT;
      float Fg = sigmoid_f(aF);
      float Og = sigmoid_f(aO);
      float Tg = tanh_f(aT);
      c = Fg * c + Og * Tg;        // faithful to ref: uses O-gate, not I-gate
      float hv2 = Og * tanh_f(c);
      hlast = hv2;
      ((_Float16*)hbuf[cur ^ 1])[j] = (_Float16)hv2;  // publish h(t+1)
      pxF = nF; pxO = nO; pxT = nT;
    }
    cur ^= 1;
  }

  // FLOAT32 output, C-order (n, j).
  if (half == 0) out[(size_t)n * H_DIM + j] = hlast;
}

extern "C" void kernel_launch(void* const* d_in, const int* in_sizes, int n_in,
                              void* d_out, int out_size, void* d_ws, size_t ws_size,
                              hipStream_t stream) {
  const void* X  = d_in[0];
  const void* E  = d_in[1];
  const void* Ww = d_in[2];
  const void* Wb = d_in[3];
  for (int i = 0; i < n_in && i < 4; ++i) {
    switch (in_sizes[i]) {
      case N_B * L_SEQ: X  = d_in[i]; break;   // 262144
      case V_SZ * EMB:  E  = d_in[i]; break;   // 8192000
      case G4 * WROW:   Ww = d_in[i]; break;   // 524288
      case G4:          Wb = d_in[i]; break;   // 1024
      default: break;
    }
  }
  float* out = (float*)d_out;

  // ws: [0,256) flags | [256, ...) Eg (32000*768 f16 = 46.9 MiB).
  uint_t*   flags = (uint_t*)d_ws;
  _Float16* Eg    = (_Float16*)((char*)d_ws + 256);

  dtype_probe<<<dim3(1), dim3(64), 0, stream>>>(
      (const uint_t*)E, (const uint_t*)X, (const uint_t*)Ww, flags);
  eg_gemm<<<dim3(V_SZ / 16), dim3(256), 0, stream>>>(E, Ww, Wb, Eg, flags);
  lstm_rec<<<dim3(N_B), dim3(512), 0, stream>>>((const int*)X, Ww, Eg, out, flags);
}